// Round 17
// baseline (236.426 us; speedup 1.0000x reference)
//
#include <hip/hip_runtime.h>

#define NN 8192
#define CIN 32
#define COUT 64
#define KF 5

typedef __attribute__((ext_vector_type(8))) short bf16x8_t;
typedef __attribute__((ext_vector_type(4))) float f32x4_t;

typedef const __attribute__((address_space(1))) void* as1_t;
typedef __attribute__((address_space(3))) void* as3_t;
__device__ __forceinline__ void gll16(const void* g, void* l) {
    __builtin_amdgcn_global_load_lds((as1_t)g, (as3_t)l, 16, 0, 0);
}

// fp32 -> bf16 RNE
__device__ __forceinline__ short f2bf(float f) {
    unsigned u = __builtin_bit_cast(unsigned, f);
    unsigned r = (u + 0x7FFFu + ((u >> 16) & 1u)) >> 16;
    return (short)(unsigned short)r;
}

__device__ __forceinline__ bf16x8_t cvt8v(f32x4_t a, f32x4_t b) {
    bf16x8_t v;
    v[0] = f2bf(a[0]); v[1] = f2bf(a[1]); v[2] = f2bf(a[2]); v[3] = f2bf(a[3]);
    v[4] = f2bf(b[0]); v[5] = f2bf(b[1]); v[6] = f2bf(b[2]); v[7] = f2bf(b[3]);
    return v;
}

// D layout (m89): col=lane&15 -> i, row=(lane>>4)*4+reg -> c
__device__ __forceinline__ void stash_partials(float* red, int wave, int g, int r,
                                               const f32x4_t& acc0, const f32x4_t& acc1) {
    const int base = wave * 512 + g * 64 + r;
#pragma unroll
    for (int t = 0; t < 4; ++t) {
        red[base + t * 16]       = acc0[t];
        red[base + t * 16 + 256] = acc1[t];
    }
}

__device__ __forceinline__ float reduce8(const float* red, int tid) {
    float s = red[tid];
#pragma unroll
    for (int w = 1; w < 8; ++w) s += red[w * 512 + tid];
    return s;
}

// ---- Pass 1 v4: block = (tile t, panel p of 1024 cols). launch_bounds(512,6)
// forces VGPR<=85 -> 3 blocks/CU (LDS 48KB allows 3). A = x read as fp32
// (panel-hot in L3), converted in-register (bit-identical to pre-cvt'd bf16).
__global__ __launch_bounds__(512, 6) void pass1_kernel(
    const float* __restrict__ L, const float* __restrict__ x,
    char* __restrict__ LbC, float* __restrict__ part)
{
    __shared__ float red[4096];                 // 16 KB
    __shared__ __align__(16) char img[32768];   // 32 KB bf16 panel image (swizzled)
    const int tid = threadIdx.x, wave = tid >> 6, lane = tid & 63;
    const int t = blockIdx.x >> 3, p = blockIdx.x & 7;
    const int i0 = t * 16, kp = p * 1024;

    // ---- Stage phase: 2 rows/wave, 4KB contiguous NT reads each
    {
        const int chunk_lo = lane >> 4;
        const int kk = (lane >> 3) & 1;
        const int g = (lane >> 1) & 3;
        const int half = (lane & 1) * 8;
#pragma unroll
        for (int rr = 0; rr < 2; ++rr) {
            const int r = wave * 2 + rr;
            const float* src = L + (size_t)(i0 + r) * NN + kp + lane * 4;
#pragma unroll
            for (int seg = 0; seg < 4; ++seg) {
                f32x4_t v = __builtin_nontemporal_load(
                    reinterpret_cast<const f32x4_t*>(src + seg * 256));
                short4 b4;
                b4.x = f2bf(v[0]); b4.y = f2bf(v[1]); b4.z = f2bf(v[2]); b4.w = f2bf(v[3]);
                const int chunk = seg * 4 + chunk_lo;
                const int byte = chunk * 2048 + kk * 1024 + g * 256 + r * 16 + half;
                const int sw = byte ^ (((byte >> 8) & 0xF) << 4);
                *reinterpret_cast<short4*>(img + sw) = b4;
            }
        }
    }
    __syncthreads();

    // ---- Dump: img -> Lb, fully linear 32KB (unswizzle on LDS read)
    {
        char* dst = LbC + (size_t)t * 262144 + p * 32768;
#pragma unroll
        for (int i = 0; i < 4; ++i) {
            const int b = tid * 16 + i * 8192;
            const int sw = b ^ (((b >> 8) & 0xF) << 4);
            *reinterpret_cast<f32x4_t*>(dst + b) =
                *reinterpret_cast<const f32x4_t*>(img + sw);
        }
    }

    // ---- T1 partial MFMA: wave covers chunks 2w, 2w+1; A from fp32 x inline-cvt
    const int g = lane >> 4, r = lane & 15;
    const float* X0 = x + (size_t)r * NN + kp;
    const float* X1 = x + (size_t)(r + 16) * NN + kp;
    f32x4_t acc0 = {0.f,0.f,0.f,0.f}, acc1 = {0.f,0.f,0.f,0.f};
#pragma unroll
    for (int cc = 0; cc < 2; ++cc) {
        const int chunk = wave * 2 + cc;
#pragma unroll
        for (int kk = 0; kk < 2; ++kk) {
            const int byte = chunk * 2048 + kk * 1024 + g * 256 + r * 16;
            const int sw = byte ^ (((byte >> 8) & 0xF) << 4);
            bf16x8_t b = *reinterpret_cast<const bf16x8_t*>(img + sw);
            const int ja = chunk * 64 + kk * 32 + g * 8;
            f32x4_t xa0 = *reinterpret_cast<const f32x4_t*>(X0 + ja);
            f32x4_t xa1 = *reinterpret_cast<const f32x4_t*>(X0 + ja + 4);
            f32x4_t xb0 = *reinterpret_cast<const f32x4_t*>(X1 + ja);
            f32x4_t xb1 = *reinterpret_cast<const f32x4_t*>(X1 + ja + 4);
            acc0 = __builtin_amdgcn_mfma_f32_16x16x32_bf16(cvt8v(xa0, xa1), b, acc0, 0, 0, 0);
            acc1 = __builtin_amdgcn_mfma_f32_16x16x32_bf16(cvt8v(xb0, xb1), b, acc1, 0, 0, 0);
        }
    }
    stash_partials(red, wave, g, r, acc0, acc1);
    __syncthreads();
    const int c = tid >> 4, il = tid & 15;
    part[(size_t)p * CIN * NN + (size_t)c * NN + i0 + il] = reduce8(red, tid);
}

// ---- T1 = sum of 8 panel partials (fixed order); write fp32 + bf16
__global__ __launch_bounds__(256) void combine8_kernel(
    const float* __restrict__ part, float* __restrict__ Tf1, short* __restrict__ Tb1)
{
    const int idx = blockIdx.x * 256 + threadIdx.x;   // quad index, CIN*NN/4
    const int NQ = CIN * NN / 4;
    float4 s = reinterpret_cast<const float4*>(part)[idx];
#pragma unroll
    for (int t = 1; t < 8; ++t) {
        float4 v = reinterpret_cast<const float4*>(part)[(size_t)t * NQ + idx];
        s.x += v.x; s.y += v.y; s.z += v.z; s.w += v.w;
    }
    reinterpret_cast<float4*>(Tf1)[idx] = s;
    short4 b;
    b.x = f2bf(s.x); b.y = f2bf(s.y); b.z = f2bf(s.z); b.w = f2bf(s.w);
    reinterpret_cast<short4*>(Tb1)[idx] = b;
}

// Mid-pass core (R15): L via depth-2 DMA ring (2KB/chunk), A via plain VGPR loads.
__device__ __forceinline__ void mid_core(const char* __restrict__ LbW,
                                         const short* __restrict__ Abase,
                                         int wave, int lane, char* stg,
                                         f32x4_t& acc0, f32x4_t& acc1)
{
    const int g = lane >> 4, r = lane & 15;
    const int kw = wave * 1024;
    const char* srcL = LbW + lane * 16;
    const short* A0 = Abase + (size_t)r * NN        + kw + g * 8;
    const short* A1 = Abase + (size_t)(r + 16) * NN + kw + g * 8;

    gll16(srcL + 0,    stg + 0);
    gll16(srcL + 1024, stg + 1024);
    gll16(srcL + 2048, stg + 2048);
    gll16(srcL + 3072, stg + 3072);

    for (int c = 0; c < 16; ++c) {
        if (c < 15) asm volatile("s_waitcnt vmcnt(2)" ::: "memory");
        else        asm volatile("s_waitcnt vmcnt(0)" ::: "memory");
        const char* Ld = stg + (c & 1) * 2048;
#pragma unroll
        for (int kk = 0; kk < 2; ++kk) {
            bf16x8_t b  = *(const bf16x8_t*)(Ld + (kk * 4 + g) * 256 + r * 16);
            bf16x8_t a0 = *(const bf16x8_t*)(A0 + c * 64 + kk * 32);
            bf16x8_t a1 = *(const bf16x8_t*)(A1 + c * 64 + kk * 32);
            acc0 = __builtin_amdgcn_mfma_f32_16x16x32_bf16(a0, b, acc0, 0, 0, 0);
            acc1 = __builtin_amdgcn_mfma_f32_16x16x32_bf16(a1, b, acc1, 0, 0, 0);
        }
        if (c < 14) {
            asm volatile("s_waitcnt lgkmcnt(0)" ::: "memory");
            const int cn = c + 2;
            gll16(srcL + cn * 2048,        stg + (cn & 1) * 2048);
            gll16(srcL + cn * 2048 + 1024, stg + (cn & 1) * 2048 + 1024);
        }
    }
}

// ---- Mid passes (2,3): T_next = 2*(Tcur @ Lb^T) - Tprev
__global__ __launch_bounds__(512, 4) void passmid_kernel(
    const char* __restrict__ LbC, const short* __restrict__ A,
    const float* __restrict__ Tprev, float* __restrict__ Tf, short* __restrict__ Tb)
{
    __shared__ float red[4096];
    __shared__ __align__(16) char stg[8][4096];
    const int tid = threadIdx.x, wave = tid >> 6, lane = tid & 63;
    const int g = lane >> 4, r = lane & 15;
    const int t = blockIdx.x, i0 = t * 16;

    f32x4_t acc0 = {0.f,0.f,0.f,0.f}, acc1 = {0.f,0.f,0.f,0.f};
    mid_core(LbC + (size_t)t * 262144 + wave * 32768, A, wave, lane, stg[wave], acc0, acc1);

    stash_partials(red, wave, g, r, acc0, acc1);
    __syncthreads();
    const int c = tid >> 4, il = tid & 15;
    const size_t off = (size_t)c * NN + i0 + il;
    const float val = 2.0f * reduce8(red, tid) - Tprev[off];
    Tf[off] = val;
    Tb[off] = f2bf(val);
}

// ---- Pass 4 + fused final einsum (T4 stays in LDS)
__global__ __launch_bounds__(512, 4) void pass4_kernel(
    const char* __restrict__ LbC, const short* __restrict__ A,
    const float* __restrict__ Tf2, const float* __restrict__ x,
    const float* __restrict__ Tf1, const float* __restrict__ Tf3,
    const float* __restrict__ theta, const float* __restrict__ bias,
    float* __restrict__ y)
{
    __shared__ float red[4096];
    __shared__ __align__(16) char stg[8][4096];
    const int tid = threadIdx.x, wave = tid >> 6, lane = tid & 63;
    const int g = lane >> 4, r = lane & 15;
    const int t = blockIdx.x, i0 = t * 16;

    f32x4_t acc0 = {0.f,0.f,0.f,0.f}, acc1 = {0.f,0.f,0.f,0.f};
    mid_core(LbC + (size_t)t * 262144 + wave * 32768, A, wave, lane, stg[wave], acc0, acc1);

    stash_partials(red, wave, g, r, acc0, acc1);
    __syncthreads();
    {   // T4 column -> red[tid] (own-slot overwrite, safe)
        const int c = tid >> 4, il = tid & 15;
        red[tid] = 2.0f * reduce8(red, tid) - Tf2[(size_t)c * NN + i0 + il];
    }
    __syncthreads();

    const int o = tid >> 4, il = tid & 15;
    float a0 = bias[o], a1 = bias[o + 32];
    for (int cc = 0; cc < CIN; ++cc) {
        const size_t off = (size_t)cc * NN + i0 + il;
        const float t0 = x[off], t1 = Tf1[off], t2 = Tf2[off], t3 = Tf3[off];
        const float t4 = red[cc * 16 + il];
        const float* th0 = theta + ((size_t)o * CIN + cc) * KF;
        const float* th1 = theta + ((size_t)(o + 32) * CIN + cc) * KF;
        a0 += t0 * th0[0] + t1 * th0[1] + t2 * th0[2] + t3 * th0[3] + t4 * th0[4];
        a1 += t0 * th1[0] + t1 * th1[1] + t2 * th1[2] + t3 * th1[3] + t4 * th1[4];
    }
    y[(size_t)o * NN + i0 + il]        = a0;
    y[(size_t)(o + 32) * NN + i0 + il] = a1;
}

extern "C" void kernel_launch(void* const* d_in, const int* in_sizes, int n_in,
                              void* d_out, int out_size, void* d_ws, size_t ws_size,
                              hipStream_t stream) {
    const float* L     = (const float*)d_in[0];
    const float* x     = (const float*)d_in[1];
    const float* theta = (const float*)d_in[2];
    const float* bias  = (const float*)d_in[3];
    float* y = (float*)d_out;

    const size_t TE = (size_t)CIN * NN;
    const size_t LE = (size_t)NN * NN;

    // ws: Lb tiled (128MB) | Tf1..Tf3 (1MB ea) | Tb1..Tb3 (0.5MB ea) | part (8MB)
    char*  LbC = (char*)d_ws;
    float* Tf1 = (float*)(LbC + LE * 2);
    float* Tf2 = Tf1 + TE;
    float* Tf3 = Tf2 + TE;
    short* Tb1 = (short*)(Tf3 + TE);
    short* Tb2 = Tb1 + TE;
    short* Tb3 = Tb2 + TE;
    float* part = (float*)(Tb3 + TE);

    pass1_kernel<<<(NN / 16) * 8, 512, 0, stream>>>(L, x, LbC, part);
    combine8_kernel<<<256, 256, 0, stream>>>(part, Tf1, Tb1);
    passmid_kernel<<<NN / 16, 512, 0, stream>>>(LbC, Tb1, x,   Tf2, Tb2);  // T2
    passmid_kernel<<<NN / 16, 512, 0, stream>>>(LbC, Tb2, Tf1, Tf3, Tb3);  // T3
    pass4_kernel<<<NN / 16, 512, 0, stream>>>(LbC, Tb3, Tf2, x, Tf1, Tf3,
                                              theta, bias, y);             // T4 + einsum
}

// Round 18
// 233.910 us; speedup vs baseline: 1.0108x; 1.0108x over previous
//
#include <hip/hip_runtime.h>

#define NN 8192
#define CIN 32
#define COUT 64
#define KF 5

typedef __attribute__((ext_vector_type(8))) short bf16x8_t;
typedef __attribute__((ext_vector_type(4))) float f32x4_t;

typedef const __attribute__((address_space(1))) void* as1_t;
typedef __attribute__((address_space(3))) void* as3_t;
__device__ __forceinline__ void gll16(const void* g, void* l) {
    __builtin_amdgcn_global_load_lds((as1_t)g, (as3_t)l, 16, 0, 0);
}

// fp32 -> bf16 RNE
__device__ __forceinline__ short f2bf(float f) {
    unsigned u = __builtin_bit_cast(unsigned, f);
    unsigned r = (u + 0x7FFFu + ((u >> 16) & 1u)) >> 16;
    return (short)(unsigned short)r;
}

__device__ __forceinline__ bf16x8_t cvt8v(f32x4_t a, f32x4_t b) {
    bf16x8_t v;
    v[0] = f2bf(a[0]); v[1] = f2bf(a[1]); v[2] = f2bf(a[2]); v[3] = f2bf(a[3]);
    v[4] = f2bf(b[0]); v[5] = f2bf(b[1]); v[6] = f2bf(b[2]); v[7] = f2bf(b[3]);
    return v;
}

// D layout (m89): col=lane&15 -> i, row=(lane>>4)*4+reg -> c
__device__ __forceinline__ void stash_partials(float* red, int wave, int g, int r,
                                               const f32x4_t& acc0, const f32x4_t& acc1) {
    const int base = wave * 512 + g * 64 + r;
#pragma unroll
    for (int t = 0; t < 4; ++t) {
        red[base + t * 16]       = acc0[t];
        red[base + t * 16 + 256] = acc1[t];
    }
}

__device__ __forceinline__ float reduce8(const float* red, int tid) {
    float s = red[tid];
#pragma unroll
    for (int w = 1; w < 8; ++w) s += red[w * 512 + tid];
    return s;
}

// ---- Pass 1 (R16 structure, launch_bounds(512,2) UNCHANGED): block = (tile t,
// panel p of 1024 cols). Stage: 4KB-contiguous NT reads -> swizzled LDS image.
// Dump: linear 32KB -> tiled Lb. T1 partial MFMA: A = x read fp32, inline cvt
// (bit-identical to pre-converted bf16; x panel slice is L3-hot).
__global__ __launch_bounds__(512, 2) void pass1_kernel(
    const float* __restrict__ L, const float* __restrict__ x,
    char* __restrict__ LbC, float* __restrict__ part)
{
    __shared__ float red[4096];                 // 16 KB
    __shared__ __align__(16) char img[32768];   // 32 KB bf16 panel image (swizzled)
    const int tid = threadIdx.x, wave = tid >> 6, lane = tid & 63;
    const int t = blockIdx.x >> 3, p = blockIdx.x & 7;
    const int i0 = t * 16, kp = p * 1024;

    // ---- Stage phase: 2 rows/wave, 4KB contiguous NT reads each
    {
        const int chunk_lo = lane >> 4;
        const int kk = (lane >> 3) & 1;
        const int g = (lane >> 1) & 3;
        const int half = (lane & 1) * 8;
#pragma unroll
        for (int rr = 0; rr < 2; ++rr) {
            const int r = wave * 2 + rr;
            const float* src = L + (size_t)(i0 + r) * NN + kp + lane * 4;
#pragma unroll
            for (int seg = 0; seg < 4; ++seg) {
                f32x4_t v = __builtin_nontemporal_load(
                    reinterpret_cast<const f32x4_t*>(src + seg * 256));
                short4 b4;
                b4.x = f2bf(v[0]); b4.y = f2bf(v[1]); b4.z = f2bf(v[2]); b4.w = f2bf(v[3]);
                const int chunk = seg * 4 + chunk_lo;
                const int byte = chunk * 2048 + kk * 1024 + g * 256 + r * 16 + half;
                const int sw = byte ^ (((byte >> 8) & 0xF) << 4);
                *reinterpret_cast<short4*>(img + sw) = b4;
            }
        }
    }
    __syncthreads();

    // ---- Dump: img -> Lb, fully linear 32KB (unswizzle on LDS read)
    {
        char* dst = LbC + (size_t)t * 262144 + p * 32768;
#pragma unroll
        for (int i = 0; i < 4; ++i) {
            const int b = tid * 16 + i * 8192;
            const int sw = b ^ (((b >> 8) & 0xF) << 4);
            *reinterpret_cast<f32x4_t*>(dst + b) =
                *reinterpret_cast<const f32x4_t*>(img + sw);
        }
    }

    // ---- T1 partial MFMA: wave covers chunks 2w, 2w+1; A from fp32 x inline-cvt
    const int g = lane >> 4, r = lane & 15;
    const float* X0 = x + (size_t)r * NN + kp;
    const float* X1 = x + (size_t)(r + 16) * NN + kp;
    f32x4_t acc0 = {0.f,0.f,0.f,0.f}, acc1 = {0.f,0.f,0.f,0.f};
#pragma unroll
    for (int cc = 0; cc < 2; ++cc) {
        const int chunk = wave * 2 + cc;
#pragma unroll
        for (int kk = 0; kk < 2; ++kk) {
            const int byte = chunk * 2048 + kk * 1024 + g * 256 + r * 16;
            const int sw = byte ^ (((byte >> 8) & 0xF) << 4);
            bf16x8_t b = *reinterpret_cast<const bf16x8_t*>(img + sw);
            const int ja = chunk * 64 + kk * 32 + g * 8;
            f32x4_t xa0 = *reinterpret_cast<const f32x4_t*>(X0 + ja);
            f32x4_t xa1 = *reinterpret_cast<const f32x4_t*>(X0 + ja + 4);
            f32x4_t xb0 = *reinterpret_cast<const f32x4_t*>(X1 + ja);
            f32x4_t xb1 = *reinterpret_cast<const f32x4_t*>(X1 + ja + 4);
            acc0 = __builtin_amdgcn_mfma_f32_16x16x32_bf16(cvt8v(xa0, xa1), b, acc0, 0, 0, 0);
            acc1 = __builtin_amdgcn_mfma_f32_16x16x32_bf16(cvt8v(xb0, xb1), b, acc1, 0, 0, 0);
        }
    }
    stash_partials(red, wave, g, r, acc0, acc1);
    __syncthreads();
    const int c = tid >> 4, il = tid & 15;
    part[(size_t)p * CIN * NN + (size_t)c * NN + i0 + il] = reduce8(red, tid);
}

// ---- T1 = sum of 8 panel partials (fixed order); write fp32 + bf16
__global__ __launch_bounds__(256) void combine8_kernel(
    const float* __restrict__ part, float* __restrict__ Tf1, short* __restrict__ Tb1)
{
    const int idx = blockIdx.x * 256 + threadIdx.x;   // quad index, CIN*NN/4
    const int NQ = CIN * NN / 4;
    float4 s = reinterpret_cast<const float4*>(part)[idx];
#pragma unroll
    for (int t = 1; t < 8; ++t) {
        float4 v = reinterpret_cast<const float4*>(part)[(size_t)t * NQ + idx];
        s.x += v.x; s.y += v.y; s.z += v.z; s.w += v.w;
    }
    reinterpret_cast<float4*>(Tf1)[idx] = s;
    short4 b;
    b.x = f2bf(s.x); b.y = f2bf(s.y); b.z = f2bf(s.z); b.w = f2bf(s.w);
    reinterpret_cast<short4*>(Tb1)[idx] = b;
}

// Mid-pass core (R15): L via depth-2 DMA ring (2KB/chunk), A via plain VGPR loads.
__device__ __forceinline__ void mid_core(const char* __restrict__ LbW,
                                         const short* __restrict__ Abase,
                                         int wave, int lane, char* stg,
                                         f32x4_t& acc0, f32x4_t& acc1)
{
    const int g = lane >> 4, r = lane & 15;
    const int kw = wave * 1024;
    const char* srcL = LbW + lane * 16;
    const short* A0 = Abase + (size_t)r * NN        + kw + g * 8;
    const short* A1 = Abase + (size_t)(r + 16) * NN + kw + g * 8;

    gll16(srcL + 0,    stg + 0);
    gll16(srcL + 1024, stg + 1024);
    gll16(srcL + 2048, stg + 2048);
    gll16(srcL + 3072, stg + 3072);

    for (int c = 0; c < 16; ++c) {
        if (c < 15) asm volatile("s_waitcnt vmcnt(2)" ::: "memory");
        else        asm volatile("s_waitcnt vmcnt(0)" ::: "memory");
        const char* Ld = stg + (c & 1) * 2048;
#pragma unroll
        for (int kk = 0; kk < 2; ++kk) {
            bf16x8_t b  = *(const bf16x8_t*)(Ld + (kk * 4 + g) * 256 + r * 16);
            bf16x8_t a0 = *(const bf16x8_t*)(A0 + c * 64 + kk * 32);
            bf16x8_t a1 = *(const bf16x8_t*)(A1 + c * 64 + kk * 32);
            acc0 = __builtin_amdgcn_mfma_f32_16x16x32_bf16(a0, b, acc0, 0, 0, 0);
            acc1 = __builtin_amdgcn_mfma_f32_16x16x32_bf16(a1, b, acc1, 0, 0, 0);
        }
        if (c < 14) {
            asm volatile("s_waitcnt lgkmcnt(0)" ::: "memory");
            const int cn = c + 2;
            gll16(srcL + cn * 2048,        stg + (cn & 1) * 2048);
            gll16(srcL + cn * 2048 + 1024, stg + (cn & 1) * 2048 + 1024);
        }
    }
}

// ---- Mid passes (2,3): T_next = 2*(Tcur @ Lb^T) - Tprev
__global__ __launch_bounds__(512, 4) void passmid_kernel(
    const char* __restrict__ LbC, const short* __restrict__ A,
    const float* __restrict__ Tprev, float* __restrict__ Tf, short* __restrict__ Tb)
{
    __shared__ float red[4096];
    __shared__ __align__(16) char stg[8][4096];
    const int tid = threadIdx.x, wave = tid >> 6, lane = tid & 63;
    const int g = lane >> 4, r = lane & 15;
    const int t = blockIdx.x, i0 = t * 16;

    f32x4_t acc0 = {0.f,0.f,0.f,0.f}, acc1 = {0.f,0.f,0.f,0.f};
    mid_core(LbC + (size_t)t * 262144 + wave * 32768, A, wave, lane, stg[wave], acc0, acc1);

    stash_partials(red, wave, g, r, acc0, acc1);
    __syncthreads();
    const int c = tid >> 4, il = tid & 15;
    const size_t off = (size_t)c * NN + i0 + il;
    const float val = 2.0f * reduce8(red, tid) - Tprev[off];
    Tf[off] = val;
    Tb[off] = f2bf(val);
}

// ---- Pass 4 + fused final einsum (T4 stays in LDS)
__global__ __launch_bounds__(512, 4) void pass4_kernel(
    const char* __restrict__ LbC, const short* __restrict__ A,
    const float* __restrict__ Tf2, const float* __restrict__ x,
    const float* __restrict__ Tf1, const float* __restrict__ Tf3,
    const float* __restrict__ theta, const float* __restrict__ bias,
    float* __restrict__ y)
{
    __shared__ float red[4096];
    __shared__ __align__(16) char stg[8][4096];
    const int tid = threadIdx.x, wave = tid >> 6, lane = tid & 63;
    const int g = lane >> 4, r = lane & 15;
    const int t = blockIdx.x, i0 = t * 16;

    f32x4_t acc0 = {0.f,0.f,0.f,0.f}, acc1 = {0.f,0.f,0.f,0.f};
    mid_core(LbC + (size_t)t * 262144 + wave * 32768, A, wave, lane, stg[wave], acc0, acc1);

    stash_partials(red, wave, g, r, acc0, acc1);
    __syncthreads();
    {   // T4 column -> red[tid] (own-slot overwrite, safe)
        const int c = tid >> 4, il = tid & 15;
        red[tid] = 2.0f * reduce8(red, tid) - Tf2[(size_t)c * NN + i0 + il];
    }
    __syncthreads();

    const int o = tid >> 4, il = tid & 15;
    float a0 = bias[o], a1 = bias[o + 32];
    for (int cc = 0; cc < CIN; ++cc) {
        const size_t off = (size_t)cc * NN + i0 + il;
        const float t0 = x[off], t1 = Tf1[off], t2 = Tf2[off], t3 = Tf3[off];
        const float t4 = red[cc * 16 + il];
        const float* th0 = theta + ((size_t)o * CIN + cc) * KF;
        const float* th1 = theta + ((size_t)(o + 32) * CIN + cc) * KF;
        a0 += t0 * th0[0] + t1 * th0[1] + t2 * th0[2] + t3 * th0[3] + t4 * th0[4];
        a1 += t0 * th1[0] + t1 * th1[1] + t2 * th1[2] + t3 * th1[3] + t4 * th1[4];
    }
    y[(size_t)o * NN + i0 + il]        = a0;
    y[(size_t)(o + 32) * NN + i0 + il] = a1;
}

extern "C" void kernel_launch(void* const* d_in, const int* in_sizes, int n_in,
                              void* d_out, int out_size, void* d_ws, size_t ws_size,
                              hipStream_t stream) {
    const float* L     = (const float*)d_in[0];
    const float* x     = (const float*)d_in[1];
    const float* theta = (const float*)d_in[2];
    const float* bias  = (const float*)d_in[3];
    float* y = (float*)d_out;

    const size_t TE = (size_t)CIN * NN;
    const size_t LE = (size_t)NN * NN;

    // ws: Lb tiled (128MB) | Tf1..Tf3 (1MB ea) | Tb1..Tb3 (0.5MB ea) | part (8MB)
    char*  LbC = (char*)d_ws;
    float* Tf1 = (float*)(LbC + LE * 2);
    float* Tf2 = Tf1 + TE;
    float* Tf3 = Tf2 + TE;
    short* Tb1 = (short*)(Tf3 + TE);
    short* Tb2 = Tb1 + TE;
    short* Tb3 = Tb2 + TE;
    float* part = (float*)(Tb3 + TE);

    pass1_kernel<<<(NN / 16) * 8, 512, 0, stream>>>(L, x, LbC, part);
    combine8_kernel<<<256, 256, 0, stream>>>(part, Tf1, Tb1);
    passmid_kernel<<<NN / 16, 512, 0, stream>>>(LbC, Tb1, x,   Tf2, Tb2);  // T2
    passmid_kernel<<<NN / 16, 512, 0, stream>>>(LbC, Tb2, Tf1, Tf3, Tb3);  // T3
    pass4_kernel<<<NN / 16, 512, 0, stream>>>(LbC, Tb3, Tf2, x, Tf1, Tf3,
                                              theta, bias, y);             // T4 + einsum
}

// Round 19
// 226.915 us; speedup vs baseline: 1.0419x; 1.0308x over previous
//
#include <hip/hip_runtime.h>

#define NN 8192
#define CIN 32
#define COUT 64
#define KF 5

typedef __attribute__((ext_vector_type(8))) short bf16x8_t;
typedef __attribute__((ext_vector_type(4))) float f32x4_t;

typedef const __attribute__((address_space(1))) void* as1_t;
typedef __attribute__((address_space(3))) void* as3_t;
__device__ __forceinline__ void gll16(const void* g, void* l) {
    __builtin_amdgcn_global_load_lds((as1_t)g, (as3_t)l, 16, 0, 0);
}

// fp32 -> bf16 RNE
__device__ __forceinline__ short f2bf(float f) {
    unsigned u = __builtin_bit_cast(unsigned, f);
    unsigned r = (u + 0x7FFFu + ((u >> 16) & 1u)) >> 16;
    return (short)(unsigned short)r;
}

// x fp32 -> bf16 (separate kernel — R18 proved folding into pass1 costs ~15us)
__global__ void cvt_kernel(const float* __restrict__ src, short* __restrict__ dst) {
    int idx = blockIdx.x * 256 + threadIdx.x;
    float4 v = reinterpret_cast<const float4*>(src)[idx];
    short4 o;
    o.x = f2bf(v.x); o.y = f2bf(v.y); o.z = f2bf(v.z); o.w = f2bf(v.w);
    reinterpret_cast<short4*>(dst)[idx] = o;
}

// D layout (m89): col=lane&15 -> i, row=(lane>>4)*4+reg -> c
__device__ __forceinline__ void stash_partials(float* red, int wave, int g, int r,
                                               const f32x4_t& acc0, const f32x4_t& acc1) {
    const int base = wave * 512 + g * 64 + r;
#pragma unroll
    for (int t = 0; t < 4; ++t) {
        red[base + t * 16]       = acc0[t];
        red[base + t * 16 + 256] = acc1[t];
    }
}

__device__ __forceinline__ float reduce8(const float* red, int tid) {
    float s = red[tid];
#pragma unroll
    for (int w = 1; w < 8; ++w) s += red[w * 512 + tid];
    return s;
}

// ---- Pass 1 v5 (R16 + panel 2048): block = (tile t, panel p of 2048 cols).
// Stage: 2 rows/wave, 8KB contiguous NT reads -> swizzled 64KB LDS image.
// Dump: fully linear 64KB -> tiled Lb (mids' layout, unchanged).
// T1 partial MFMA: A = Tb0 bf16 (R16-proven); wave covers chunks 4w..4w+3.
__global__ __launch_bounds__(512, 2) void pass1_kernel(
    const float* __restrict__ L, const short* __restrict__ Tb0,
    char* __restrict__ LbC, float* __restrict__ part)
{
    __shared__ float red[4096];                 // 16 KB
    __shared__ __align__(16) char img[65536];   // 64 KB bf16 panel image (swizzled)
    const int tid = threadIdx.x, wave = tid >> 6, lane = tid & 63;
    const int t = blockIdx.x >> 2, p = blockIdx.x & 3;
    const int i0 = t * 16, kp = p * 2048;

    // ---- Stage phase: 2 rows/wave, 8KB contiguous NT reads each
    {
        const int chunk_lo = lane >> 4;          // 0..3 within a seg
        const int kk = (lane >> 3) & 1;
        const int g = (lane >> 1) & 3;
        const int half = (lane & 1) * 8;
#pragma unroll
        for (int rr = 0; rr < 2; ++rr) {
            const int r = wave * 2 + rr;
            const float* src = L + (size_t)(i0 + r) * NN + kp + lane * 4;
#pragma unroll
            for (int seg = 0; seg < 8; ++seg) {
                f32x4_t v = __builtin_nontemporal_load(
                    reinterpret_cast<const f32x4_t*>(src + seg * 256));
                short4 b4;
                b4.x = f2bf(v[0]); b4.y = f2bf(v[1]); b4.z = f2bf(v[2]); b4.w = f2bf(v[3]);
                const int chunk = seg * 4 + chunk_lo;          // 0..31
                const int byte = chunk * 2048 + kk * 1024 + g * 256 + r * 16 + half;
                const int sw = byte ^ (((byte >> 8) & 0xF) << 4);
                *reinterpret_cast<short4*>(img + sw) = b4;
            }
        }
    }
    __syncthreads();

    // ---- Dump: img -> Lb, fully linear 64KB (unswizzle on LDS read)
    {
        char* dst = LbC + (size_t)t * 262144 + p * 65536;
#pragma unroll
        for (int i = 0; i < 8; ++i) {
            const int b = tid * 16 + i * 8192;
            const int sw = b ^ (((b >> 8) & 0xF) << 4);
            *reinterpret_cast<f32x4_t*>(dst + b) =
                *reinterpret_cast<const f32x4_t*>(img + sw);
        }
    }

    // ---- T1 partial MFMA: wave covers chunks 4w..4w+3 of the panel
    const int g = lane >> 4, r = lane & 15;
    const short* A0 = Tb0 + (size_t)r * NN + kp;
    const short* A1 = Tb0 + (size_t)(r + 16) * NN + kp;
    f32x4_t acc0 = {0.f,0.f,0.f,0.f}, acc1 = {0.f,0.f,0.f,0.f};
#pragma unroll
    for (int cc = 0; cc < 4; ++cc) {
        const int chunk = wave * 4 + cc;
#pragma unroll
        for (int kk = 0; kk < 2; ++kk) {
            const int byte = chunk * 2048 + kk * 1024 + g * 256 + r * 16;
            const int sw = byte ^ (((byte >> 8) & 0xF) << 4);
            bf16x8_t b = *reinterpret_cast<const bf16x8_t*>(img + sw);
            const int ja = chunk * 64 + kk * 32 + g * 8;
            bf16x8_t a0 = *reinterpret_cast<const bf16x8_t*>(A0 + ja);
            bf16x8_t a1 = *reinterpret_cast<const bf16x8_t*>(A1 + ja);
            acc0 = __builtin_amdgcn_mfma_f32_16x16x32_bf16(a0, b, acc0, 0, 0, 0);
            acc1 = __builtin_amdgcn_mfma_f32_16x16x32_bf16(a1, b, acc1, 0, 0, 0);
        }
    }
    stash_partials(red, wave, g, r, acc0, acc1);
    __syncthreads();
    const int c = tid >> 4, il = tid & 15;
    part[(size_t)p * CIN * NN + (size_t)c * NN + i0 + il] = reduce8(red, tid);
}

// ---- T1 = sum of 4 panel partials (fixed order); write fp32 + bf16
__global__ __launch_bounds__(256) void combine4_kernel(
    const float* __restrict__ part, float* __restrict__ Tf1, short* __restrict__ Tb1)
{
    const int idx = blockIdx.x * 256 + threadIdx.x;   // quad index, CIN*NN/4
    const int NQ = CIN * NN / 4;
    float4 s = reinterpret_cast<const float4*>(part)[idx];
#pragma unroll
    for (int t = 1; t < 4; ++t) {
        float4 v = reinterpret_cast<const float4*>(part)[(size_t)t * NQ + idx];
        s.x += v.x; s.y += v.y; s.z += v.z; s.w += v.w;
    }
    reinterpret_cast<float4*>(Tf1)[idx] = s;
    short4 b;
    b.x = f2bf(s.x); b.y = f2bf(s.y); b.z = f2bf(s.z); b.w = f2bf(s.w);
    reinterpret_cast<short4*>(Tb1)[idx] = b;
}

// Mid-pass core (R15): L via depth-2 DMA ring (2KB/chunk), A via plain VGPR loads.
__device__ __forceinline__ void mid_core(const char* __restrict__ LbW,
                                         const short* __restrict__ Abase,
                                         int wave, int lane, char* stg,
                                         f32x4_t& acc0, f32x4_t& acc1)
{
    const int g = lane >> 4, r = lane & 15;
    const int kw = wave * 1024;
    const char* srcL = LbW + lane * 16;
    const short* A0 = Abase + (size_t)r * NN        + kw + g * 8;
    const short* A1 = Abase + (size_t)(r + 16) * NN + kw + g * 8;

    gll16(srcL + 0,    stg + 0);
    gll16(srcL + 1024, stg + 1024);
    gll16(srcL + 2048, stg + 2048);
    gll16(srcL + 3072, stg + 3072);

    for (int c = 0; c < 16; ++c) {
        if (c < 15) asm volatile("s_waitcnt vmcnt(2)" ::: "memory");
        else        asm volatile("s_waitcnt vmcnt(0)" ::: "memory");
        const char* Ld = stg + (c & 1) * 2048;
#pragma unroll
        for (int kk = 0; kk < 2; ++kk) {
            bf16x8_t b  = *(const bf16x8_t*)(Ld + (kk * 4 + g) * 256 + r * 16);
            bf16x8_t a0 = *(const bf16x8_t*)(A0 + c * 64 + kk * 32);
            bf16x8_t a1 = *(const bf16x8_t*)(A1 + c * 64 + kk * 32);
            acc0 = __builtin_amdgcn_mfma_f32_16x16x32_bf16(a0, b, acc0, 0, 0, 0);
            acc1 = __builtin_amdgcn_mfma_f32_16x16x32_bf16(a1, b, acc1, 0, 0, 0);
        }
        if (c < 14) {
            asm volatile("s_waitcnt lgkmcnt(0)" ::: "memory");
            const int cn = c + 2;
            gll16(srcL + cn * 2048,        stg + (cn & 1) * 2048);
            gll16(srcL + cn * 2048 + 1024, stg + (cn & 1) * 2048 + 1024);
        }
    }
}

// ---- Mid passes (2,3): T_next = 2*(Tcur @ Lb^T) - Tprev
__global__ __launch_bounds__(512, 4) void passmid_kernel(
    const char* __restrict__ LbC, const short* __restrict__ A,
    const float* __restrict__ Tprev, float* __restrict__ Tf, short* __restrict__ Tb)
{
    __shared__ float red[4096];
    __shared__ __align__(16) char stg[8][4096];
    const int tid = threadIdx.x, wave = tid >> 6, lane = tid & 63;
    const int g = lane >> 4, r = lane & 15;
    const int t = blockIdx.x, i0 = t * 16;

    f32x4_t acc0 = {0.f,0.f,0.f,0.f}, acc1 = {0.f,0.f,0.f,0.f};
    mid_core(LbC + (size_t)t * 262144 + wave * 32768, A, wave, lane, stg[wave], acc0, acc1);

    stash_partials(red, wave, g, r, acc0, acc1);
    __syncthreads();
    const int c = tid >> 4, il = tid & 15;
    const size_t off = (size_t)c * NN + i0 + il;
    const float val = 2.0f * reduce8(red, tid) - Tprev[off];
    Tf[off] = val;
    Tb[off] = f2bf(val);
}

// ---- Pass 4 + fused final einsum (T4 stays in LDS)
__global__ __launch_bounds__(512, 4) void pass4_kernel(
    const char* __restrict__ LbC, const short* __restrict__ A,
    const float* __restrict__ Tf2, const float* __restrict__ x,
    const float* __restrict__ Tf1, const float* __restrict__ Tf3,
    const float* __restrict__ theta, const float* __restrict__ bias,
    float* __restrict__ y)
{
    __shared__ float red[4096];
    __shared__ __align__(16) char stg[8][4096];
    const int tid = threadIdx.x, wave = tid >> 6, lane = tid & 63;
    const int g = lane >> 4, r = lane & 15;
    const int t = blockIdx.x, i0 = t * 16;

    f32x4_t acc0 = {0.f,0.f,0.f,0.f}, acc1 = {0.f,0.f,0.f,0.f};
    mid_core(LbC + (size_t)t * 262144 + wave * 32768, A, wave, lane, stg[wave], acc0, acc1);

    stash_partials(red, wave, g, r, acc0, acc1);
    __syncthreads();
    {   // T4 column -> red[tid] (own-slot overwrite, safe)
        const int c = tid >> 4, il = tid & 15;
        red[tid] = 2.0f * reduce8(red, tid) - Tf2[(size_t)c * NN + i0 + il];
    }
    __syncthreads();

    const int o = tid >> 4, il = tid & 15;
    float a0 = bias[o], a1 = bias[o + 32];
    for (int cc = 0; cc < CIN; ++cc) {
        const size_t off = (size_t)cc * NN + i0 + il;
        const float t0 = x[off], t1 = Tf1[off], t2 = Tf2[off], t3 = Tf3[off];
        const float t4 = red[cc * 16 + il];
        const float* th0 = theta + ((size_t)o * CIN + cc) * KF;
        const float* th1 = theta + ((size_t)(o + 32) * CIN + cc) * KF;
        a0 += t0 * th0[0] + t1 * th0[1] + t2 * th0[2] + t3 * th0[3] + t4 * th0[4];
        a1 += t0 * th1[0] + t1 * th1[1] + t2 * th1[2] + t3 * th1[3] + t4 * th1[4];
    }
    y[(size_t)o * NN + i0 + il]        = a0;
    y[(size_t)(o + 32) * NN + i0 + il] = a1;
}

extern "C" void kernel_launch(void* const* d_in, const int* in_sizes, int n_in,
                              void* d_out, int out_size, void* d_ws, size_t ws_size,
                              hipStream_t stream) {
    const float* L     = (const float*)d_in[0];
    const float* x     = (const float*)d_in[1];
    const float* theta = (const float*)d_in[2];
    const float* bias  = (const float*)d_in[3];
    float* y = (float*)d_out;

    const size_t TE = (size_t)CIN * NN;
    const size_t LE = (size_t)NN * NN;

    // ws: Lb tiled (128MB) | Tf1..Tf3 (1MB ea) | Tb0..Tb3 (0.5MB ea) | part (4MB)
    char*  LbC = (char*)d_ws;
    float* Tf1 = (float*)(LbC + LE * 2);
    float* Tf2 = Tf1 + TE;
    float* Tf3 = Tf2 + TE;
    short* Tb0 = (short*)(Tf3 + TE);
    short* Tb1 = Tb0 + TE;
    short* Tb2 = Tb1 + TE;
    short* Tb3 = Tb2 + TE;
    float* part = (float*)(Tb3 + TE);

    cvt_kernel<<<256, 256, 0, stream>>>(x, Tb0);
    pass1_kernel<<<(NN / 16) * 4, 512, 0, stream>>>(L, Tb0, LbC, part);
    combine4_kernel<<<256, 256, 0, stream>>>(part, Tf1, Tb1);
    passmid_kernel<<<NN / 16, 512, 0, stream>>>(LbC, Tb1, x,   Tf2, Tb2);  // T2
    passmid_kernel<<<NN / 16, 512, 0, stream>>>(LbC, Tb2, Tf1, Tf3, Tb3);  // T3
    pass4_kernel<<<NN / 16, 512, 0, stream>>>(LbC, Tb3, Tf2, x, Tf1, Tf3,
                                              theta, bias, y);             // T4 + einsum
}

// Round 20
// 218.968 us; speedup vs baseline: 1.0797x; 1.0363x over previous
//
#include <hip/hip_runtime.h>

#define NN 8192
#define CIN 32
#define COUT 64
#define KF 5

typedef __attribute__((ext_vector_type(8))) short bf16x8_t;
typedef __attribute__((ext_vector_type(4))) float f32x4_t;

typedef const __attribute__((address_space(1))) void* as1_t;
typedef __attribute__((address_space(3))) void* as3_t;
__device__ __forceinline__ void gll16(const void* g, void* l) {
    __builtin_amdgcn_global_load_lds((as1_t)g, (as3_t)l, 16, 0, 0);
}

// fp32 -> bf16 RNE
__device__ __forceinline__ short f2bf(float f) {
    unsigned u = __builtin_bit_cast(unsigned, f);
    unsigned r = (u + 0x7FFFu + ((u >> 16) & 1u)) >> 16;
    return (short)(unsigned short)r;
}

// x fp32 -> bf16 (separate kernel — R18 proved folding into pass1 costs ~15us)
__global__ void cvt_kernel(const float* __restrict__ src, short* __restrict__ dst) {
    int idx = blockIdx.x * 256 + threadIdx.x;
    float4 v = reinterpret_cast<const float4*>(src)[idx];
    short4 o;
    o.x = f2bf(v.x); o.y = f2bf(v.y); o.z = f2bf(v.z); o.w = f2bf(v.w);
    reinterpret_cast<short4*>(dst)[idx] = o;
}

// D layout (m89): col=lane&15 -> i, row=(lane>>4)*4+reg -> c
__device__ __forceinline__ void stash_partials(float* red, int wave, int g, int r,
                                               const f32x4_t& acc0, const f32x4_t& acc1) {
    const int base = wave * 512 + g * 64 + r;
#pragma unroll
    for (int t = 0; t < 4; ++t) {
        red[base + t * 16]       = acc0[t];
        red[base + t * 16 + 256] = acc1[t];
    }
}

__device__ __forceinline__ float reduce8(const float* red, int tid) {
    float s = red[tid];
#pragma unroll
    for (int w = 1; w < 8; ++w) s += red[w * 512 + tid];
    return s;
}

// ---- Pass 1 (R16-proven, 218.9us config): block = (tile t, panel p of 1024 cols).
// Stage: 2 rows/wave, 4KB contiguous NT reads -> swizzled 32KB LDS image.
// Dump: fully linear 32KB -> tiled Lb. T1 partial MFMA: A = Tb0 bf16.
__global__ __launch_bounds__(512, 2) void pass1_kernel(
    const float* __restrict__ L, const short* __restrict__ Tb0,
    char* __restrict__ LbC, float* __restrict__ part)
{
    __shared__ float red[4096];                 // 16 KB
    __shared__ __align__(16) char img[32768];   // 32 KB bf16 panel image (swizzled)
    const int tid = threadIdx.x, wave = tid >> 6, lane = tid & 63;
    const int t = blockIdx.x >> 3, p = blockIdx.x & 7;
    const int i0 = t * 16, kp = p * 1024;

    // ---- Stage phase: 2 rows/wave, 4KB contiguous NT reads each
    {
        const int chunk_lo = lane >> 4;
        const int kk = (lane >> 3) & 1;
        const int g = (lane >> 1) & 3;
        const int half = (lane & 1) * 8;
#pragma unroll
        for (int rr = 0; rr < 2; ++rr) {
            const int r = wave * 2 + rr;
            const float* src = L + (size_t)(i0 + r) * NN + kp + lane * 4;
#pragma unroll
            for (int seg = 0; seg < 4; ++seg) {
                f32x4_t v = __builtin_nontemporal_load(
                    reinterpret_cast<const f32x4_t*>(src + seg * 256));
                short4 b4;
                b4.x = f2bf(v[0]); b4.y = f2bf(v[1]); b4.z = f2bf(v[2]); b4.w = f2bf(v[3]);
                const int chunk = seg * 4 + chunk_lo;
                const int byte = chunk * 2048 + kk * 1024 + g * 256 + r * 16 + half;
                const int sw = byte ^ (((byte >> 8) & 0xF) << 4);
                *reinterpret_cast<short4*>(img + sw) = b4;
            }
        }
    }
    __syncthreads();

    // ---- Dump: img -> Lb, fully linear 32KB (unswizzle on LDS read)
    {
        char* dst = LbC + (size_t)t * 262144 + p * 32768;
#pragma unroll
        for (int i = 0; i < 4; ++i) {
            const int b = tid * 16 + i * 8192;
            const int sw = b ^ (((b >> 8) & 0xF) << 4);
            *reinterpret_cast<f32x4_t*>(dst + b) =
                *reinterpret_cast<const f32x4_t*>(img + sw);
        }
    }

    // ---- T1 partial MFMA: wave covers chunks 2w, 2w+1 of the panel
    const int g = lane >> 4, r = lane & 15;
    const short* A0 = Tb0 + (size_t)r * NN + kp;
    const short* A1 = Tb0 + (size_t)(r + 16) * NN + kp;
    f32x4_t acc0 = {0.f,0.f,0.f,0.f}, acc1 = {0.f,0.f,0.f,0.f};
#pragma unroll
    for (int cc = 0; cc < 2; ++cc) {
        const int chunk = wave * 2 + cc;
#pragma unroll
        for (int kk = 0; kk < 2; ++kk) {
            const int byte = chunk * 2048 + kk * 1024 + g * 256 + r * 16;
            const int sw = byte ^ (((byte >> 8) & 0xF) << 4);
            bf16x8_t b = *reinterpret_cast<const bf16x8_t*>(img + sw);
            const int ja = chunk * 64 + kk * 32 + g * 8;
            bf16x8_t a0 = *reinterpret_cast<const bf16x8_t*>(A0 + ja);
            bf16x8_t a1 = *reinterpret_cast<const bf16x8_t*>(A1 + ja);
            acc0 = __builtin_amdgcn_mfma_f32_16x16x32_bf16(a0, b, acc0, 0, 0, 0);
            acc1 = __builtin_amdgcn_mfma_f32_16x16x32_bf16(a1, b, acc1, 0, 0, 0);
        }
    }
    stash_partials(red, wave, g, r, acc0, acc1);
    __syncthreads();
    const int c = tid >> 4, il = tid & 15;
    part[(size_t)p * CIN * NN + (size_t)c * NN + i0 + il] = reduce8(red, tid);
}

// ---- T1 = sum of 8 panel partials (fixed order); write fp32 + bf16
__global__ __launch_bounds__(256) void combine8_kernel(
    const float* __restrict__ part, float* __restrict__ Tf1, short* __restrict__ Tb1)
{
    const int idx = blockIdx.x * 256 + threadIdx.x;   // quad index, CIN*NN/4
    const int NQ = CIN * NN / 4;
    float4 s = reinterpret_cast<const float4*>(part)[idx];
#pragma unroll
    for (int t = 1; t < 8; ++t) {
        float4 v = reinterpret_cast<const float4*>(part)[(size_t)t * NQ + idx];
        s.x += v.x; s.y += v.y; s.z += v.z; s.w += v.w;
    }
    reinterpret_cast<float4*>(Tf1)[idx] = s;
    short4 b;
    b.x = f2bf(s.x); b.y = f2bf(s.y); b.z = f2bf(s.z); b.w = f2bf(s.w);
    reinterpret_cast<short4*>(Tb1)[idx] = b;
}

// Mid-pass core (R15): L via depth-2 DMA ring (2KB/chunk), A via plain VGPR loads.
__device__ __forceinline__ void mid_core(const char* __restrict__ LbW,
                                         const short* __restrict__ Abase,
                                         int wave, int lane, char* stg,
                                         f32x4_t& acc0, f32x4_t& acc1)
{
    const int g = lane >> 4, r = lane & 15;
    const int kw = wave * 1024;
    const char* srcL = LbW + lane * 16;
    const short* A0 = Abase + (size_t)r * NN        + kw + g * 8;
    const short* A1 = Abase + (size_t)(r + 16) * NN + kw + g * 8;

    gll16(srcL + 0,    stg + 0);
    gll16(srcL + 1024, stg + 1024);
    gll16(srcL + 2048, stg + 2048);
    gll16(srcL + 3072, stg + 3072);

    for (int c = 0; c < 16; ++c) {
        if (c < 15) asm volatile("s_waitcnt vmcnt(2)" ::: "memory");
        else        asm volatile("s_waitcnt vmcnt(0)" ::: "memory");
        const char* Ld = stg + (c & 1) * 2048;
#pragma unroll
        for (int kk = 0; kk < 2; ++kk) {
            bf16x8_t b  = *(const bf16x8_t*)(Ld + (kk * 4 + g) * 256 + r * 16);
            bf16x8_t a0 = *(const bf16x8_t*)(A0 + c * 64 + kk * 32);
            bf16x8_t a1 = *(const bf16x8_t*)(A1 + c * 64 + kk * 32);
            acc0 = __builtin_amdgcn_mfma_f32_16x16x32_bf16(a0, b, acc0, 0, 0, 0);
            acc1 = __builtin_amdgcn_mfma_f32_16x16x32_bf16(a1, b, acc1, 0, 0, 0);
        }
        if (c < 14) {
            asm volatile("s_waitcnt lgkmcnt(0)" ::: "memory");
            const int cn = c + 2;
            gll16(srcL + cn * 2048,        stg + (cn & 1) * 2048);
            gll16(srcL + cn * 2048 + 1024, stg + (cn & 1) * 2048 + 1024);
        }
    }
}

// ---- Mid passes (2,3): T_next = 2*(Tcur @ Lb^T) - Tprev
__global__ __launch_bounds__(512, 4) void passmid_kernel(
    const char* __restrict__ LbC, const short* __restrict__ A,
    const float* __restrict__ Tprev, float* __restrict__ Tf, short* __restrict__ Tb)
{
    __shared__ float red[4096];
    __shared__ __align__(16) char stg[8][4096];
    const int tid = threadIdx.x, wave = tid >> 6, lane = tid & 63;
    const int g = lane >> 4, r = lane & 15;
    const int t = blockIdx.x, i0 = t * 16;

    f32x4_t acc0 = {0.f,0.f,0.f,0.f}, acc1 = {0.f,0.f,0.f,0.f};
    mid_core(LbC + (size_t)t * 262144 + wave * 32768, A, wave, lane, stg[wave], acc0, acc1);

    stash_partials(red, wave, g, r, acc0, acc1);
    __syncthreads();
    const int c = tid >> 4, il = tid & 15;
    const size_t off = (size_t)c * NN + i0 + il;
    const float val = 2.0f * reduce8(red, tid) - Tprev[off];
    Tf[off] = val;
    Tb[off] = f2bf(val);
}

// ---- Pass 4 + fused final einsum (T4 stays in LDS)
__global__ __launch_bounds__(512, 4) void pass4_kernel(
    const char* __restrict__ LbC, const short* __restrict__ A,
    const float* __restrict__ Tf2, const float* __restrict__ x,
    const float* __restrict__ Tf1, const float* __restrict__ Tf3,
    const float* __restrict__ theta, const float* __restrict__ bias,
    float* __restrict__ y)
{
    __shared__ float red[4096];
    __shared__ __align__(16) char stg[8][4096];
    const int tid = threadIdx.x, wave = tid >> 6, lane = tid & 63;
    const int g = lane >> 4, r = lane & 15;
    const int t = blockIdx.x, i0 = t * 16;

    f32x4_t acc0 = {0.f,0.f,0.f,0.f}, acc1 = {0.f,0.f,0.f,0.f};
    mid_core(LbC + (size_t)t * 262144 + wave * 32768, A, wave, lane, stg[wave], acc0, acc1);

    stash_partials(red, wave, g, r, acc0, acc1);
    __syncthreads();
    {   // T4 column -> red[tid] (own-slot overwrite, safe)
        const int c = tid >> 4, il = tid & 15;
        red[tid] = 2.0f * reduce8(red, tid) - Tf2[(size_t)c * NN + i0 + il];
    }
    __syncthreads();

    const int o = tid >> 4, il = tid & 15;
    float a0 = bias[o], a1 = bias[o + 32];
    for (int cc = 0; cc < CIN; ++cc) {
        const size_t off = (size_t)cc * NN + i0 + il;
        const float t0 = x[off], t1 = Tf1[off], t2 = Tf2[off], t3 = Tf3[off];
        const float t4 = red[cc * 16 + il];
        const float* th0 = theta + ((size_t)o * CIN + cc) * KF;
        const float* th1 = theta + ((size_t)(o + 32) * CIN + cc) * KF;
        a0 += t0 * th0[0] + t1 * th0[1] + t2 * th0[2] + t3 * th0[3] + t4 * th0[4];
        a1 += t0 * th1[0] + t1 * th1[1] + t2 * th1[2] + t3 * th1[3] + t4 * th1[4];
    }
    y[(size_t)o * NN + i0 + il]        = a0;
    y[(size_t)(o + 32) * NN + i0 + il] = a1;
}

extern "C" void kernel_launch(void* const* d_in, const int* in_sizes, int n_in,
                              void* d_out, int out_size, void* d_ws, size_t ws_size,
                              hipStream_t stream) {
    const float* L     = (const float*)d_in[0];
    const float* x     = (const float*)d_in[1];
    const float* theta = (const float*)d_in[2];
    const float* bias  = (const float*)d_in[3];
    float* y = (float*)d_out;

    const size_t TE = (size_t)CIN * NN;
    const size_t LE = (size_t)NN * NN;

    // ws: Lb tiled (128MB) | Tf1..Tf3 (1MB ea) | Tb0..Tb3 (0.5MB ea) | part (8MB)
    char*  LbC = (char*)d_ws;
    float* Tf1 = (float*)(LbC + LE * 2);
    float* Tf2 = Tf1 + TE;
    float* Tf3 = Tf2 + TE;
    short* Tb0 = (short*)(Tf3 + TE);
    short* Tb1 = Tb0 + TE;
    short* Tb2 = Tb1 + TE;
    short* Tb3 = Tb2 + TE;
    float* part = (float*)(Tb3 + TE);

    cvt_kernel<<<256, 256, 0, stream>>>(x, Tb0);
    pass1_kernel<<<(NN / 16) * 8, 512, 0, stream>>>(L, Tb0, LbC, part);
    combine8_kernel<<<256, 256, 0, stream>>>(part, Tf1, Tb1);
    passmid_kernel<<<NN / 16, 512, 0, stream>>>(LbC, Tb1, x,   Tf2, Tb2);  // T2
    passmid_kernel<<<NN / 16, 512, 0, stream>>>(LbC, Tb2, Tf1, Tf3, Tb3);  // T3
    pass4_kernel<<<NN / 16, 512, 0, stream>>>(LbC, Tb3, Tf2, x, Tf1, Tf3,
                                              theta, bias, y);             // T4 + einsum
}